// Round 14
// baseline (141.775 us; speedup 1.0000x reference)
//
#include <hip/hip_runtime.h>

typedef unsigned short u16;
typedef unsigned int   u32;
typedef __attribute__((ext_vector_type(2)))  unsigned u32x2;
typedef __attribute__((ext_vector_type(4)))  float  f32x4;
typedef __attribute__((ext_vector_type(8)))  short  s16x8;

__device__ __forceinline__ u16 f2bf(float f) {
  unsigned u = __builtin_bit_cast(unsigned, f);
  u += 0x7FFFu + ((u >> 16) & 1u);
  return (u16)(u >> 16);
}

__device__ __forceinline__ float exp2g(float x) { return __builtin_amdgcn_exp2f(x); }

__device__ __forceinline__ void gload16(const void* g, void* l) {
  __builtin_amdgcn_global_load_lds(
      (const __attribute__((address_space(1))) void*)g,
      (__attribute__((address_space(3))) void*)l, 16, 0, 0);
}

// ---------------- LayerNorm (fp32 in -> bf16 out) ----------------
__global__ __launch_bounds__(256) void ln_kernel(
    const float* __restrict__ x, const float* __restrict__ gamma,
    const float* __restrict__ beta, u16* __restrict__ xn)
{
  const int row = blockIdx.x, tid = threadIdx.x;
  const float* xr = x + (size_t)row * 1024;
  float4 v = *(const float4*)(xr + tid * 4);
  float s  = v.x + v.y + v.z + v.w;
  float s2 = v.x*v.x + v.y*v.y + v.z*v.z + v.w*v.w;
#pragma unroll
  for (int off = 32; off >= 1; off >>= 1) {
    s  += __shfl_xor(s,  off);
    s2 += __shfl_xor(s2, off);
  }
  __shared__ float red[8];
  const int w = tid >> 6, l = tid & 63;
  if (l == 0) { red[w] = s; red[w + 4] = s2; }
  __syncthreads();
  s  = red[0] + red[1] + red[2] + red[3];
  s2 = red[4] + red[5] + red[6] + red[7];
  const float mu  = s * (1.0f / 1024.0f);
  const float var = s2 * (1.0f / 1024.0f) - mu * mu;
  const float rs  = rsqrtf(var + 1e-5f);
  float4 g  = *(const float4*)(gamma + tid * 4);
  float4 be = *(const float4*)(beta  + tid * 4);
  ushort4 o;
  o.x = f2bf((v.x - mu) * rs * g.x + be.x);
  o.y = f2bf((v.y - mu) * rs * g.y + be.y);
  o.z = f2bf((v.z - mu) * rs * g.z + be.z);
  o.w = f2bf((v.w - mu) * rs * g.w + be.w);
  *(ushort4*)(xn + (size_t)row * 1024 + tid * 4) = o;
}

// ---------------- transpose + fp32->bf16 convert ----------------
__global__ void transpose_cvt(const float* __restrict__ in, u16* __restrict__ out,
                              int R, int C)
{
  __shared__ float t[32][33];
  const int bc = blockIdx.x * 32, br = blockIdx.y * 32;
  const int x = threadIdx.x;
#pragma unroll
  for (int i = threadIdx.y; i < 32; i += 8)
    t[i][x] = in[(size_t)(br + i) * C + bc + x];
  __syncthreads();
#pragma unroll
  for (int i = threadIdx.y; i < 32; i += 8)
    out[(size_t)(bc + i) * R + br + x] = f2bf(t[x][i]);
}

// ---------------- GEMM 256x256, BK=64, 8 waves, 1 barrier/K-tile ----------------
// C[M][N] = A[M][K] * Bt[N][K]^T + bias, bf16 out. Requires M%256==0, N%256==0, K%64==0.
__global__ __launch_bounds__(512, 2) void gemm256_bt(
    const u16* __restrict__ A, const u16* __restrict__ Bt,
    const float* __restrict__ bias, u16* __restrict__ C,
    int M, int N, int K, int NBX)
{
  __shared__ u16 As[2][16384];   // [256 rows][64 k] ; row = 8 chunks of 16B, XOR (row&7)
  __shared__ u16 Bs[2][16384];

  const int tid = threadIdx.x;
  const int w = tid >> 6, l = tid & 63;
  const int g = l >> 4, li = l & 15;

  // bijective XCD swizzle (grid % 8 == 0)
  const int nwg = NBX * ((M + 255) >> 8);
  const int cpx = nwg >> 3;
  const int lb  = (blockIdx.x & 7) * cpx + (blockIdx.x >> 3);
  const int bn  = (lb % NBX) * 256;
  const int bm  = (lb / NBX) * 256;

  const int wr = (w >> 2) * 128, wc = (w & 3) * 64;

  f32x4 acc[8][4] = {};

  // staging: per matrix 2048 chunks of 16B; thread handles chunks c = i*512 + tid
  const u16* pa[4]; const u16* pb[4];
#pragma unroll
  for (int i = 0; i < 4; ++i) {
    const int c = i * 512 + tid, row = c >> 3, slot = c & 7;
    pa[i] = A  + (size_t)(bm + row) * K + 8 * (slot ^ (row & 7));
    pb[i] = Bt + (size_t)(bn + row) * K + 8 * (slot ^ (row & 7));
  }

  auto stage = [&](int nb, int kt) {
#pragma unroll
    for (int i = 0; i < 4; ++i) {
      u16* da = &As[nb][(i * 512 + w * 64) * 8];
      u16* db = &Bs[nb][(i * 512 + w * 64) * 8];
      gload16(pa[i] + kt, da);
      gload16(pb[i] + kt, db);
    }
  };

  stage(0, 0);
  __syncthreads();

  int buf = 0;
  const int NT = K >> 6;
  for (int t = 0; t < NT; ++t) {
    if (t + 1 < NT) stage(buf ^ 1, (t + 1) << 6);   // front-loaded prefetch

    const u16* as = &As[buf][0];
    const u16* bs = &Bs[buf][0];

    // hoist B fragments (shared by all 4 quadrant phases)
    s16x8 bf[4][2];
#pragma unroll
    for (int n = 0; n < 4; ++n)
#pragma unroll
      for (int kd = 0; kd < 2; ++kd) {
        const int row = wc + n * 16 + li;
        bf[n][kd] = *(const s16x8*)(bs + row * 64 + 8 * ((4 * kd + g) ^ (row & 7)));
      }

    // 4 quadrant phases: rows wr + mq*32 .. +31
#pragma unroll
    for (int mq = 0; mq < 4; ++mq) {
      s16x8 af[2][2];
#pragma unroll
      for (int m2 = 0; m2 < 2; ++m2)
#pragma unroll
        for (int kd = 0; kd < 2; ++kd) {
          const int row = wr + mq * 32 + m2 * 16 + li;
          af[m2][kd] = *(const s16x8*)(as + row * 64 + 8 * ((4 * kd + g) ^ (row & 7)));
        }
      __builtin_amdgcn_s_setprio(1);
#pragma unroll
      for (int m2 = 0; m2 < 2; ++m2)
#pragma unroll
        for (int n = 0; n < 4; ++n)
#pragma unroll
          for (int kd = 0; kd < 2; ++kd)
            acc[mq * 2 + m2][n] = __builtin_amdgcn_mfma_f32_16x16x32_bf16(
                af[m2][kd], bf[n][kd], acc[mq * 2 + m2][n], 0, 0, 0);
      __builtin_amdgcn_s_setprio(0);
    }

    __syncthreads();   // own vmcnt drained -> buf^1 staged everywhere; all reads of buf done
    buf ^= 1;
  }

  // epilogue
#pragma unroll
  for (int n = 0; n < 4; ++n) {
    const int col = bn + wc + n * 16 + li;
    const float bv = bias[col];
#pragma unroll
    for (int m = 0; m < 8; ++m) {
      const int row0 = bm + wr + m * 16 + g * 4;
#pragma unroll
      for (int r = 0; r < 4; ++r)
        C[(size_t)(row0 + r) * N + col] = f2bf(acc[m][n][r] + bv);
    }
  }
}

// ---------------- GEMM (2-phase dbuf, r12-verified): C = A * Bt^T + bias ----------------
__device__ __forceinline__ void store_out(float* p, float v) { *p = v; }
__device__ __forceinline__ void store_out(u16* p, float v)   { *p = f2bf(v); }

template <typename OutT>
__global__ __launch_bounds__(256) void gemm_bt(
    const u16* __restrict__ A, const u16* __restrict__ Bt,
    const float* __restrict__ bias, OutT* __restrict__ C,
    int M, int N, int K)
{
  __shared__ u16 As[2][128 * 32];
  __shared__ u16 Bs[2][128 * 32];
  const int tid = threadIdx.x;
  const int w = tid >> 6, l = tid & 63;
  const int g = l >> 4, li = l & 15;
  const int bm = blockIdx.y * 128, bn = blockIdx.x * 128;
  const int wr = (w >> 1) * 64, wc = (w & 1) * 64;

  f32x4 acc[4][4] = {};

  const int ar0 = tid >> 2,          as0 = tid & 3;
  const int ar1 = (tid + 256) >> 2,  as1 = (tid + 256) & 3;
  const u16* pa0 = A  + (size_t)(bm + ar0) * K + 8 * (as0 ^ (ar0 & 3));
  const u16* pa1 = A  + (size_t)(bm + ar1) * K + 8 * (as1 ^ (ar1 & 3));
  const u16* pb0 = Bt + (size_t)(bn + ar0) * K + 8 * (as0 ^ (ar0 & 3));
  const u16* pb1 = Bt + (size_t)(bn + ar1) * K + 8 * (as1 ^ (ar1 & 3));

  auto stage = [&](int b, int kt) {
    gload16(pa0 + kt, &As[b][w * 512]);
    gload16(pa1 + kt, &As[b][2048 + w * 512]);
    gload16(pb0 + kt, &Bs[b][w * 512]);
    gload16(pb1 + kt, &Bs[b][2048 + w * 512]);
  };

  stage(0, 0);

  int buf = 0;
  for (int kt = 0; kt < K; kt += 32) {
    __syncthreads();
    if (kt + 32 < K) stage(buf ^ 1, kt + 32);

    const u16* as = &As[buf][0];
    const u16* bs = &Bs[buf][0];

    s16x8 af[4], bf[4];
#pragma unroll
    for (int m = 0; m < 4; ++m) {
      const int row = wr + m * 16 + li;
      af[m] = *(const s16x8*)(as + row * 32 + 8 * (g ^ (row & 3)));
    }
#pragma unroll
    for (int n = 0; n < 4; ++n) {
      const int row = wc + n * 16 + li;
      bf[n] = *(const s16x8*)(bs + row * 32 + 8 * (g ^ (row & 3)));
    }
    __builtin_amdgcn_s_setprio(1);
#pragma unroll
    for (int m = 0; m < 4; ++m)
#pragma unroll
      for (int n = 0; n < 4; ++n)
        acc[m][n] = __builtin_amdgcn_mfma_f32_16x16x32_bf16(af[m], bf[n], acc[m][n], 0, 0, 0);
    __builtin_amdgcn_s_setprio(0);

    buf ^= 1;
  }

#pragma unroll
  for (int n = 0; n < 4; ++n) {
    const int col = bn + wc + n * 16 + li;
    const float bv = bias[col];
#pragma unroll
    for (int m = 0; m < 4; ++m) {
      const int row0 = bm + wr + m * 16 + g * 4;
#pragma unroll
      for (int r = 0; r < 4; ++r)
        store_out(C + (size_t)(row0 + r) * N + col, acc[m][n][r] + bv);
    }
  }
}

// ---------------- flash attention (r13-verified, frozen) ----------------
__global__ __launch_bounds__(256, 4) void attn_kernel(
    const u16* __restrict__ qkv, u16* __restrict__ outp)
{
  __shared__ u16 Ks[2][4096];   // [kv][d] dbuf, 16B chunks XOR-swizzled by (kv&7)  (verified)
  __shared__ u16 Vt[4096];      // [d][kv] single, byte XOR ((d^(d>>3))&7)<<4       (verified)
  __shared__ u16 Pl[4 * 1024];  // per-wave P[q=li][64kv], byte XOR ((li&7)<<4)

  const int tid = threadIdx.x;
  const int w = tid >> 6, l = tid & 63;
  const int g = l >> 4, li = l & 15;

  // T1: bijective XCD swizzle (1024 = 8 * 128)
  const int lb = (blockIdx.x & 7) * 128 + (blockIdx.x >> 3);
  const int qt = lb & 31;
  const int h  = (lb >> 5) & 15;
  const int bb = lb >> 9;
  const size_t baserow = (size_t)bb * 2048;

  const int qbase = qt * 64 + w * 16;
  const u16* qp = qkv + (baserow + qbase + li) * 3072 + h * 64 + 8 * g;
  const s16x8 qf0 = *(const s16x8*)(qp);
  const s16x8 qf1 = *(const s16x8*)(qp + 32);

  const int kr0 = tid >> 3,         kc0 = tid & 7;
  const int kr1 = (tid + 256) >> 3, kc1 = (tid + 256) & 7;
  const u16* kg0 = qkv + (baserow + kr0) * 3072 + 1024 + h * 64 + 8 * (kc0 ^ (kr0 & 7));
  const u16* kg1 = qkv + (baserow + kr1) * 3072 + 1024 + h * 64 + 8 * (kc1 ^ (kr1 & 7));

  const int vp = tid >> 3, dg = tid & 7;
  const u16* vgA = qkv + (baserow + 2 * vp)     * 3072 + 2048 + h * 64 + 8 * dg;
  const u16* vgB = qkv + (baserow + 2 * vp + 1) * 3072 + 2048 + h * 64 + 8 * dg;

  auto issueK = [&](int b, int t) {
    const size_t koff = (size_t)t * (64 * 3072);
    gload16(kg0 + koff, &Ks[b][w * 512]);
    gload16(kg1 + koff, &Ks[b][2048 + w * 512]);
  };

  const float C1  = 0.18033688f;   // 0.125 * log2(e)
  const float THR = 11.5416f;      // 8 * log2(e)
  float M = -1e30f;
  f32x4 o[4] = {}, os = {};

  s16x8 ones;
#pragma unroll
  for (int j = 0; j < 8; ++j) ones[j] = (short)0x3F80;

  char* Pw = (char*)(Pl + w * 1024);
  const int pswz = (li & 7) << 4;

  issueK(0, 0);
  s16x8 va = *(const s16x8*)vgA;
  s16x8 vb = *(const s16x8*)vgB;

  int buf = 0;
  for (int t = 0; t < 32; ++t) {
#pragma unroll
    for (int j = 0; j < 8; ++j) {
      const int d = 8 * dg + j;
      const u32 val = (u32)(u16)va[j] | ((u32)(u16)vb[j] << 16);
      *(u32*)((char*)Vt + d * 128 + ((4 * vp) ^ ((((d ^ (d >> 3)) & 7)) << 4))) = val;
    }
    __syncthreads();

    if (t < 31) {
      issueK(buf ^ 1, t + 1);
      const size_t koff = (size_t)(t + 1) * (64 * 3072);
      va = *(const s16x8*)(vgA + koff);
      vb = *(const s16x8*)(vgB + koff);
    }

    const u16* kb = &Ks[buf][0];

    f32x4 s[4] = {};
    __builtin_amdgcn_s_setprio(1);
#pragma unroll
    for (int nk = 0; nk < 4; ++nk) {
      const int kvr = nk * 16 + li;
      const s16x8 kf0 = *(const s16x8*)((const char*)kb + kvr * 128 + 16 * ((0 + g) ^ (kvr & 7)));
      const s16x8 kf1 = *(const s16x8*)((const char*)kb + kvr * 128 + 16 * ((4 + g) ^ (kvr & 7)));
      s[nk] = __builtin_amdgcn_mfma_f32_16x16x32_bf16(kf0, qf0, s[nk], 0, 0, 0);
      s[nk] = __builtin_amdgcn_mfma_f32_16x16x32_bf16(kf1, qf1, s[nk], 0, 0, 0);
    }
    __builtin_amdgcn_s_setprio(0);

    float lm = fmaxf(fmaxf(s[0][0], s[0][1]), fmaxf(s[0][2], s[0][3]));
#pragma unroll
    for (int nk = 1; nk < 4; ++nk)
      lm = fmaxf(lm, fmaxf(fmaxf(s[nk][0], s[nk][1]), fmaxf(s[nk][2], s[nk][3])));
    lm = fmaxf(lm, __shfl_xor(lm, 16));
    lm = fmaxf(lm, __shfl_xor(lm, 32));
    lm *= C1;

    if (__any(lm > M + THR)) {
      const float mn = fmaxf(M, lm);
      const float a = exp2g(M - mn);
      M = mn;
      os[0] *= a;
#pragma unroll
      for (int nd = 0; nd < 4; ++nd)
#pragma unroll
        for (int r = 0; r < 4; ++r) o[nd][r] *= a;
    }

#pragma unroll
    for (int nk = 0; nk < 4; ++nk)
#pragma unroll
      for (int r = 0; r < 4; ++r)
        s[nk][r] = exp2g(fmaf(s[nk][r], C1, -M));

#pragma unroll
    for (int nk = 0; nk < 4; ++nk) {
      u32 lo, hi;
      asm("v_cvt_pk_bf16_f32 %0, %1, %2" : "=v"(lo) : "v"(s[nk][0]), "v"(s[nk][1]));
      asm("v_cvt_pk_bf16_f32 %0, %1, %2" : "=v"(hi) : "v"(s[nk][2]), "v"(s[nk][3]));
      *(u32x2*)(Pw + li * 128 + ((nk * 32 + 8 * g) ^ pswz)) = (u32x2){lo, hi};
    }
    asm volatile("s_waitcnt lgkmcnt(0)" ::: "memory");

    __builtin_amdgcn_s_setprio(1);
#pragma unroll
    for (int ks = 0; ks < 2; ++ks) {
      const s16x8 pf = *(const s16x8*)(Pw + li * 128 + ((ks * 64 + 16 * g) ^ pswz));
#pragma unroll
      for (int nd = 0; nd < 4; ++nd) {
        const int d = nd * 16 + li;
        const s16x8 vf = *(const s16x8*)((char*)Vt + d * 128 + ((ks * 64 + 16 * g) ^ (((d ^ (d >> 3)) & 7) << 4)));
        o[nd] = __builtin_amdgcn_mfma_f32_16x16x32_bf16(vf, pf, o[nd], 0, 0, 0);
      }
      os = __builtin_amdgcn_mfma_f32_16x16x32_bf16(ones, pf, os, 0, 0, 0);
    }
    __builtin_amdgcn_s_setprio(0);

    __syncthreads();
    buf ^= 1;
  }

  const float inv = 1.0f / os[0];
  const size_t row = baserow + qbase + li;
#pragma unroll
  for (int nd = 0; nd < 4; ++nd) {
    ushort4 st;
    st.x = f2bf(o[nd][0] * inv);
    st.y = f2bf(o[nd][1] * inv);
    st.z = f2bf(o[nd][2] * inv);
    st.w = f2bf(o[nd][3] * inv);
    *(ushort4*)(outp + row * 1024 + h * 64 + nd * 16 + 4 * g) = st;
  }
}

// ---------------- launcher ----------------
extern "C" void kernel_launch(void* const* d_in, const int* in_sizes, int n_in,
                              void* d_out, int out_size, void* d_ws, size_t ws_size,
                              hipStream_t stream)
{
  const float* x     = (const float*)d_in[0];
  const float* gamma = (const float*)d_in[1];
  const float* beta  = (const float*)d_in[2];
  const float* Wqkv  = (const float*)d_in[3];
  const float* bqkv  = (const float*)d_in[4];
  const float* Wout  = (const float*)d_in[5];
  const float* bout  = (const float*)d_in[6];
  float* out = (float*)d_out;

  char* ws = (char*)d_ws;
  u16* xn     = (u16*)(ws);                       // 8 MB  [4096][1024]
  u16* wqkv_t = (u16*)(ws + ((size_t)8  << 20));  // 6 MB  [3072][1024]
  u16* wout_t = (u16*)(ws + ((size_t)14 << 20));  // 2 MB  [1024][1024]
  u16* qkv    = (u16*)(ws + ((size_t)16 << 20));  // 24 MB [4096][3072]
  u16* attn   = (u16*)(ws + ((size_t)40 << 20));  // 8 MB  [4096][1024]

  ln_kernel<<<4096, 256, 0, stream>>>(x, gamma, beta, xn);
  transpose_cvt<<<dim3(96, 32), dim3(32, 8), 0, stream>>>(Wqkv, wqkv_t, 1024, 3072);
  transpose_cvt<<<dim3(32, 32), dim3(32, 8), 0, stream>>>(Wout, wout_t, 1024, 1024);
  gemm256_bt<<<192, 512, 0, stream>>>(xn, wqkv_t, bqkv, qkv, 4096, 3072, 1024, 12);
  attn_kernel<<<1024, 256, 0, stream>>>(qkv, attn);
  gemm_bt<float><<<dim3(8, 32), 256, 0, stream>>>(attn, wout_t, bout, out, 4096, 1024, 1024);
}

// Round 15
// 137.297 us; speedup vs baseline: 1.0326x; 1.0326x over previous
//
#include <hip/hip_runtime.h>

typedef unsigned short u16;
typedef unsigned int   u32;
typedef __attribute__((ext_vector_type(2)))  unsigned u32x2;
typedef __attribute__((ext_vector_type(4)))  float  f32x4;
typedef __attribute__((ext_vector_type(8)))  short  s16x8;

__device__ __forceinline__ u16 f2bf(float f) {
  unsigned u = __builtin_bit_cast(unsigned, f);
  u += 0x7FFFu + ((u >> 16) & 1u);
  return (u16)(u >> 16);
}

__device__ __forceinline__ float exp2g(float x) { return __builtin_amdgcn_exp2f(x); }

__device__ __forceinline__ void gload16(const void* g, void* l) {
  __builtin_amdgcn_global_load_lds(
      (const __attribute__((address_space(1))) void*)g,
      (__attribute__((address_space(3))) void*)l, 16, 0, 0);
}

// ---------------- LayerNorm (fp32 in -> bf16 out) ----------------
__global__ __launch_bounds__(256) void ln_kernel(
    const float* __restrict__ x, const float* __restrict__ gamma,
    const float* __restrict__ beta, u16* __restrict__ xn)
{
  const int row = blockIdx.x, tid = threadIdx.x;
  const float* xr = x + (size_t)row * 1024;
  float4 v = *(const float4*)(xr + tid * 4);
  float s  = v.x + v.y + v.z + v.w;
  float s2 = v.x*v.x + v.y*v.y + v.z*v.z + v.w*v.w;
#pragma unroll
  for (int off = 32; off >= 1; off >>= 1) {
    s  += __shfl_xor(s,  off);
    s2 += __shfl_xor(s2, off);
  }
  __shared__ float red[8];
  const int w = tid >> 6, l = tid & 63;
  if (l == 0) { red[w] = s; red[w + 4] = s2; }
  __syncthreads();
  s  = red[0] + red[1] + red[2] + red[3];
  s2 = red[4] + red[5] + red[6] + red[7];
  const float mu  = s * (1.0f / 1024.0f);
  const float var = s2 * (1.0f / 1024.0f) - mu * mu;
  const float rs  = rsqrtf(var + 1e-5f);
  float4 g  = *(const float4*)(gamma + tid * 4);
  float4 be = *(const float4*)(beta  + tid * 4);
  ushort4 o;
  o.x = f2bf((v.x - mu) * rs * g.x + be.x);
  o.y = f2bf((v.y - mu) * rs * g.y + be.y);
  o.z = f2bf((v.z - mu) * rs * g.z + be.z);
  o.w = f2bf((v.w - mu) * rs * g.w + be.w);
  *(ushort4*)(xn + (size_t)row * 1024 + tid * 4) = o;
}

// ---------------- transpose + fp32->bf16 convert ----------------
__global__ void transpose_cvt(const float* __restrict__ in, u16* __restrict__ out,
                              int R, int C)
{
  __shared__ float t[32][33];
  const int bc = blockIdx.x * 32, br = blockIdx.y * 32;
  const int x = threadIdx.x;
#pragma unroll
  for (int i = threadIdx.y; i < 32; i += 8)
    t[i][x] = in[(size_t)(br + i) * C + bc + x];
  __syncthreads();
#pragma unroll
  for (int i = threadIdx.y; i < 32; i += 8)
    out[(size_t)(bc + i) * R + br + x] = f2bf(t[x][i]);
}

// ---------------- GEMM (2-phase dbuf, r12-verified): C = A * Bt^T + bias ----------------
__device__ __forceinline__ void store_out(float* p, float v) { *p = v; }
__device__ __forceinline__ void store_out(u16* p, float v)   { *p = f2bf(v); }

template <typename OutT>
__global__ __launch_bounds__(256) void gemm_bt(
    const u16* __restrict__ A, const u16* __restrict__ Bt,
    const float* __restrict__ bias, OutT* __restrict__ C,
    int M, int N, int K)
{
  __shared__ u16 As[2][128 * 32];
  __shared__ u16 Bs[2][128 * 32];
  const int tid = threadIdx.x;
  const int w = tid >> 6, l = tid & 63;
  const int g = l >> 4, li = l & 15;
  const int bm = blockIdx.y * 128, bn = blockIdx.x * 128;
  const int wr = (w >> 1) * 64, wc = (w & 1) * 64;

  f32x4 acc[4][4] = {};

  const int ar0 = tid >> 2,          as0 = tid & 3;
  const int ar1 = (tid + 256) >> 2,  as1 = (tid + 256) & 3;
  const u16* pa0 = A  + (size_t)(bm + ar0) * K + 8 * (as0 ^ (ar0 & 3));
  const u16* pa1 = A  + (size_t)(bm + ar1) * K + 8 * (as1 ^ (ar1 & 3));
  const u16* pb0 = Bt + (size_t)(bn + ar0) * K + 8 * (as0 ^ (ar0 & 3));
  const u16* pb1 = Bt + (size_t)(bn + ar1) * K + 8 * (as1 ^ (ar1 & 3));

  auto stage = [&](int b, int kt) {
    gload16(pa0 + kt, &As[b][w * 512]);
    gload16(pa1 + kt, &As[b][2048 + w * 512]);
    gload16(pb0 + kt, &Bs[b][w * 512]);
    gload16(pb1 + kt, &Bs[b][2048 + w * 512]);
  };

  stage(0, 0);

  int buf = 0;
  for (int kt = 0; kt < K; kt += 32) {
    __syncthreads();
    if (kt + 32 < K) stage(buf ^ 1, kt + 32);

    const u16* as = &As[buf][0];
    const u16* bs = &Bs[buf][0];

    s16x8 af[4], bf[4];
#pragma unroll
    for (int m = 0; m < 4; ++m) {
      const int row = wr + m * 16 + li;
      af[m] = *(const s16x8*)(as + row * 32 + 8 * (g ^ (row & 3)));
    }
#pragma unroll
    for (int n = 0; n < 4; ++n) {
      const int row = wc + n * 16 + li;
      bf[n] = *(const s16x8*)(bs + row * 32 + 8 * (g ^ (row & 3)));
    }
    __builtin_amdgcn_s_setprio(1);
#pragma unroll
    for (int m = 0; m < 4; ++m)
#pragma unroll
      for (int n = 0; n < 4; ++n)
        acc[m][n] = __builtin_amdgcn_mfma_f32_16x16x32_bf16(af[m], bf[n], acc[m][n], 0, 0, 0);
    __builtin_amdgcn_s_setprio(0);

    buf ^= 1;
  }

#pragma unroll
  for (int n = 0; n < 4; ++n) {
    const int col = bn + wc + n * 16 + li;
    const float bv = bias[col];
#pragma unroll
    for (int m = 0; m < 4; ++m) {
      const int row0 = bm + wr + m * 16 + g * 4;
#pragma unroll
      for (int r = 0; r < 4; ++r)
        store_out(C + (size_t)(row0 + r) * N + col, acc[m][n][r] + bv);
    }
  }
}

// ---------------- flash attention: single barrier/tile (dbuf K + dbuf Vt) ----------------
// qkv: [4096][3072] bf16; out: [4096][1024] bf16
// grid 1024 (32 qt x 16 h x 2 b); block = 4 waves; each wave owns 16 q-rows (q = li).
__global__ __launch_bounds__(256, 4) void attn_kernel(
    const u16* __restrict__ qkv, u16* __restrict__ outp)
{
  __shared__ u16 Ks[2][4096];   // [kv][d] dbuf, 16B chunks XOR-swizzled by (kv&7)  (verified)
  __shared__ u16 Vt[2][4096];   // [d][kv] dbuf, byte XOR ((d^(d>>3))&7)<<4         (verified)
  __shared__ u16 Pl[4 * 1024];  // per-wave P[q=li][64kv], byte XOR ((li&7)<<4)     (verified)

  const int tid = threadIdx.x;
  const int w = tid >> 6, l = tid & 63;
  const int g = l >> 4, li = l & 15;

  // T1: bijective XCD swizzle (1024 = 8 * 128)
  const int lb = (blockIdx.x & 7) * 128 + (blockIdx.x >> 3);
  const int qt = lb & 31;
  const int h  = (lb >> 5) & 15;
  const int bb = lb >> 9;
  const size_t baserow = (size_t)bb * 2048;

  const int qbase = qt * 64 + w * 16;
  const u16* qp = qkv + (baserow + qbase + li) * 3072 + h * 64 + 8 * g;
  const s16x8 qf0 = *(const s16x8*)(qp);
  const s16x8 qf1 = *(const s16x8*)(qp + 32);

  const int kr0 = tid >> 3,         kc0 = tid & 7;
  const int kr1 = (tid + 256) >> 3, kc1 = (tid + 256) & 7;
  const u16* kg0 = qkv + (baserow + kr0) * 3072 + 1024 + h * 64 + 8 * (kc0 ^ (kr0 & 7));
  const u16* kg1 = qkv + (baserow + kr1) * 3072 + 1024 + h * 64 + 8 * (kc1 ^ (kr1 & 7));

  const int vp = tid >> 3, dg = tid & 7;
  const u16* vgA = qkv + (baserow + 2 * vp)     * 3072 + 2048 + h * 64 + 8 * dg;
  const u16* vgB = qkv + (baserow + 2 * vp + 1) * 3072 + 2048 + h * 64 + 8 * dg;

  auto issueK = [&](int b, int t) {
    const size_t koff = (size_t)t * (64 * 3072);
    gload16(kg0 + koff, &Ks[b][w * 512]);
    gload16(kg1 + koff, &Ks[b][2048 + w * 512]);
  };

  const float C1  = 0.18033688f;   // 0.125 * log2(e)
  const float THR = 11.5416f;      // 8 * log2(e)
  float M = -1e30f;
  f32x4 o[4] = {}, os = {};        // o[nd][r] = O[q=li][d=nd*16+4g+r]; os[0] = rowsum

  s16x8 ones;
#pragma unroll
  for (int j = 0; j < 8; ++j) ones[j] = (short)0x3F80;   // bf16 1.0

  char* Pw = (char*)(Pl + w * 1024);
  const int pswz = (li & 7) << 4;

  // prologue: prefetch tile 0
  issueK(0, 0);
  s16x8 va = *(const s16x8*)vgA;
  s16x8 vb = *(const s16x8*)vgB;

  int buf = 0;
  for (int t = 0; t < 32; ++t) {
    // V regs (tile t) -> Vt[buf]; paired-kv b32 writes, verified swizzle involution
#pragma unroll
    for (int j = 0; j < 8; ++j) {
      const int d = 8 * dg + j;
      const u32 val = (u32)(u16)va[j] | ((u32)(u16)vb[j] << 16);
      *(u32*)((char*)&Vt[buf][0] + d * 128 + ((4 * vp) ^ ((((d ^ (d >> 3)) & 7)) << 4))) = val;
    }
    // SINGLE barrier per tile: publishes Vt[buf] writes; drains K[buf] gload (vmcnt);
    // also proves all waves finished reading Ks[buf]/Vt[buf] last time (program order:
    // compute(buf)@t-2-parity precedes this wave's V-write@t precedes this barrier).
    __syncthreads();

    if (t < 31) {      // prefetch next tile (lands at next iteration's barrier)
      issueK(buf ^ 1, t + 1);
      const size_t koff = (size_t)(t + 1) * (64 * 3072);
      va = *(const s16x8*)(vgA + koff);
      vb = *(const s16x8*)(vgB + koff);
    }

    const u16* kb = &Ks[buf][0];

    // ---- S^T = K . Q^T (swapped operands) ----
    f32x4 s[4] = {};
    __builtin_amdgcn_s_setprio(1);
#pragma unroll
    for (int nk = 0; nk < 4; ++nk) {
      const int kvr = nk * 16 + li;
      const s16x8 kf0 = *(const s16x8*)((const char*)kb + kvr * 128 + 16 * ((0 + g) ^ (kvr & 7)));
      const s16x8 kf1 = *(const s16x8*)((const char*)kb + kvr * 128 + 16 * ((4 + g) ^ (kvr & 7)));
      s[nk] = __builtin_amdgcn_mfma_f32_16x16x32_bf16(kf0, qf0, s[nk], 0, 0, 0);
      s[nk] = __builtin_amdgcn_mfma_f32_16x16x32_bf16(kf1, qf1, s[nk], 0, 0, 0);
    }
    __builtin_amdgcn_s_setprio(0);

    // ---- softmax: lane-local max + 2 shuffles ----
    float lm = fmaxf(fmaxf(s[0][0], s[0][1]), fmaxf(s[0][2], s[0][3]));
#pragma unroll
    for (int nk = 1; nk < 4; ++nk)
      lm = fmaxf(lm, fmaxf(fmaxf(s[nk][0], s[nk][1]), fmaxf(s[nk][2], s[nk][3])));
    lm = fmaxf(lm, __shfl_xor(lm, 16));
    lm = fmaxf(lm, __shfl_xor(lm, 32));
    lm *= C1;

    if (__any(lm > M + THR)) {       // T13 defer-max (rare)
      const float mn = fmaxf(M, lm);
      const float a = exp2g(M - mn);
      M = mn;
      os[0] *= a;
#pragma unroll
      for (int nd = 0; nd < 4; ++nd)
#pragma unroll
        for (int r = 0; r < 4; ++r) o[nd][r] *= a;
    }

    // ---- exp2 in place ----
#pragma unroll
    for (int nk = 0; nk < 4; ++nk)
#pragma unroll
      for (int r = 0; r < 4; ++r)
        s[nk][r] = exp2g(fmaf(s[nk][r], C1, -M));

    // ---- P -> LDS: cvt_pk pairs, 4x ds_write_b64 ----
#pragma unroll
    for (int nk = 0; nk < 4; ++nk) {
      u32 lo, hi;
      asm("v_cvt_pk_bf16_f32 %0, %1, %2" : "=v"(lo) : "v"(s[nk][0]), "v"(s[nk][1]));
      asm("v_cvt_pk_bf16_f32 %0, %1, %2" : "=v"(hi) : "v"(s[nk][2]), "v"(s[nk][3]));
      *(u32x2*)(Pw + li * 128 + ((nk * 32 + 8 * g) ^ pswz)) = (u32x2){lo, hi};
    }
    asm volatile("s_waitcnt lgkmcnt(0)" ::: "memory");

    // ---- O^T += V^T . P^T ----
    __builtin_amdgcn_s_setprio(1);
#pragma unroll
    for (int ks = 0; ks < 2; ++ks) {
      const s16x8 pf = *(const s16x8*)(Pw + li * 128 + ((ks * 64 + 16 * g) ^ pswz));
#pragma unroll
      for (int nd = 0; nd < 4; ++nd) {
        const int d = nd * 16 + li;
        const s16x8 vf = *(const s16x8*)((char*)&Vt[buf][0] + d * 128 + ((ks * 64 + 16 * g) ^ (((d ^ (d >> 3)) & 7) << 4)));
        o[nd] = __builtin_amdgcn_mfma_f32_16x16x32_bf16(vf, pf, o[nd], 0, 0, 0);
      }
      os = __builtin_amdgcn_mfma_f32_16x16x32_bf16(ones, pf, os, 0, 0, 0);
    }
    __builtin_amdgcn_s_setprio(0);

    buf ^= 1;
  }

  // ---- epilogue ----
  const float inv = 1.0f / os[0];
  const size_t row = baserow + qbase + li;
#pragma unroll
  for (int nd = 0; nd < 4; ++nd) {
    ushort4 st;
    st.x = f2bf(o[nd][0] * inv);
    st.y = f2bf(o[nd][1] * inv);
    st.z = f2bf(o[nd][2] * inv);
    st.w = f2bf(o[nd][3] * inv);
    *(ushort4*)(outp + row * 1024 + h * 64 + nd * 16 + 4 * g) = st;
  }
}

// ---------------- launcher ----------------
extern "C" void kernel_launch(void* const* d_in, const int* in_sizes, int n_in,
                              void* d_out, int out_size, void* d_ws, size_t ws_size,
                              hipStream_t stream)
{
  const float* x     = (const float*)d_in[0];
  const float* gamma = (const float*)d_in[1];
  const float* beta  = (const float*)d_in[2];
  const float* Wqkv  = (const float*)d_in[3];
  const float* bqkv  = (const float*)d_in[4];
  const float* Wout  = (const float*)d_in[5];
  const float* bout  = (const float*)d_in[6];
  float* out = (float*)d_out;

  char* ws = (char*)d_ws;
  u16* xn     = (u16*)(ws);                       // 8 MB  [4096][1024]
  u16* wqkv_t = (u16*)(ws + ((size_t)8  << 20));  // 6 MB  [3072][1024]
  u16* wout_t = (u16*)(ws + ((size_t)14 << 20));  // 2 MB  [1024][1024]
  u16* qkv    = (u16*)(ws + ((size_t)16 << 20));  // 24 MB [4096][3072]
  u16* attn   = (u16*)(ws + ((size_t)40 << 20));  // 8 MB  [4096][1024]

  ln_kernel<<<4096, 256, 0, stream>>>(x, gamma, beta, xn);
  transpose_cvt<<<dim3(96, 32), dim3(32, 8), 0, stream>>>(Wqkv, wqkv_t, 1024, 3072);
  transpose_cvt<<<dim3(32, 32), dim3(32, 8), 0, stream>>>(Wout, wout_t, 1024, 1024);
  gemm_bt<u16><<<dim3(24, 32), 256, 0, stream>>>(xn, wqkv_t, bqkv, qkv, 4096, 3072, 1024);
  attn_kernel<<<1024, 256, 0, stream>>>(qkv, attn);
  gemm_bt<float><<<dim3(8, 32), 256, 0, stream>>>(attn, wout_t, bout, out, 4096, 1024, 1024);
}

// Round 16
// 132.850 us; speedup vs baseline: 1.0672x; 1.0335x over previous
//
#include <hip/hip_runtime.h>

typedef unsigned short u16;
typedef unsigned int   u32;
typedef __attribute__((ext_vector_type(2)))  unsigned u32x2;
typedef __attribute__((ext_vector_type(4)))  float  f32x4;
typedef __attribute__((ext_vector_type(8)))  short  s16x8;

__device__ __forceinline__ u16 f2bf(float f) {
  unsigned u = __builtin_bit_cast(unsigned, f);
  u += 0x7FFFu + ((u >> 16) & 1u);
  return (u16)(u >> 16);
}

__device__ __forceinline__ float exp2g(float x) { return __builtin_amdgcn_exp2f(x); }

__device__ __forceinline__ void gload16(const void* g, void* l) {
  __builtin_amdgcn_global_load_lds(
      (const __attribute__((address_space(1))) void*)g,
      (__attribute__((address_space(3))) void*)l, 16, 0, 0);
}

// ---------------- LayerNorm (fp32 in -> bf16 out) ----------------
__global__ __launch_bounds__(256) void ln_kernel(
    const float* __restrict__ x, const float* __restrict__ gamma,
    const float* __restrict__ beta, u16* __restrict__ xn)
{
  const int row = blockIdx.x, tid = threadIdx.x;
  const float* xr = x + (size_t)row * 1024;
  float4 v = *(const float4*)(xr + tid * 4);
  float s  = v.x + v.y + v.z + v.w;
  float s2 = v.x*v.x + v.y*v.y + v.z*v.z + v.w*v.w;
#pragma unroll
  for (int off = 32; off >= 1; off >>= 1) {
    s  += __shfl_xor(s,  off);
    s2 += __shfl_xor(s2, off);
  }
  __shared__ float red[8];
  const int w = tid >> 6, l = tid & 63;
  if (l == 0) { red[w] = s; red[w + 4] = s2; }
  __syncthreads();
  s  = red[0] + red[1] + red[2] + red[3];
  s2 = red[4] + red[5] + red[6] + red[7];
  const float mu  = s * (1.0f / 1024.0f);
  const float var = s2 * (1.0f / 1024.0f) - mu * mu;
  const float rs  = rsqrtf(var + 1e-5f);
  float4 g  = *(const float4*)(gamma + tid * 4);
  float4 be = *(const float4*)(beta  + tid * 4);
  ushort4 o;
  o.x = f2bf((v.x - mu) * rs * g.x + be.x);
  o.y = f2bf((v.y - mu) * rs * g.y + be.y);
  o.z = f2bf((v.z - mu) * rs * g.z + be.z);
  o.w = f2bf((v.w - mu) * rs * g.w + be.w);
  *(ushort4*)(xn + (size_t)row * 1024 + tid * 4) = o;
}

// ---------------- transpose + fp32->bf16 convert ----------------
__global__ void transpose_cvt(const float* __restrict__ in, u16* __restrict__ out,
                              int R, int C)
{
  __shared__ float t[32][33];
  const int bc = blockIdx.x * 32, br = blockIdx.y * 32;
  const int x = threadIdx.x;
#pragma unroll
  for (int i = threadIdx.y; i < 32; i += 8)
    t[i][x] = in[(size_t)(br + i) * C + bc + x];
  __syncthreads();
#pragma unroll
  for (int i = threadIdx.y; i < 32; i += 8)
    out[(size_t)(bc + i) * R + br + x] = f2bf(t[x][i]);
}

// ---------------- GEMM 128x128 (2-phase dbuf, r12-verified) ----------------
__device__ __forceinline__ void store_out(float* p, float v) { *p = v; }
__device__ __forceinline__ void store_out(u16* p, float v)   { *p = f2bf(v); }

template <typename OutT>
__global__ __launch_bounds__(256) void gemm_bt(
    const u16* __restrict__ A, const u16* __restrict__ Bt,
    const float* __restrict__ bias, OutT* __restrict__ C,
    int M, int N, int K)
{
  __shared__ u16 As[2][128 * 32];
  __shared__ u16 Bs[2][128 * 32];
  const int tid = threadIdx.x;
  const int w = tid >> 6, l = tid & 63;
  const int g = l >> 4, li = l & 15;
  const int bm = blockIdx.y * 128, bn = blockIdx.x * 128;
  const int wr = (w >> 1) * 64, wc = (w & 1) * 64;

  f32x4 acc[4][4] = {};

  const int ar0 = tid >> 2,          as0 = tid & 3;
  const int ar1 = (tid + 256) >> 2,  as1 = (tid + 256) & 3;
  const u16* pa0 = A  + (size_t)(bm + ar0) * K + 8 * (as0 ^ (ar0 & 3));
  const u16* pa1 = A  + (size_t)(bm + ar1) * K + 8 * (as1 ^ (ar1 & 3));
  const u16* pb0 = Bt + (size_t)(bn + ar0) * K + 8 * (as0 ^ (ar0 & 3));
  const u16* pb1 = Bt + (size_t)(bn + ar1) * K + 8 * (as1 ^ (ar1 & 3));

  auto stage = [&](int b, int kt) {
    gload16(pa0 + kt, &As[b][w * 512]);
    gload16(pa1 + kt, &As[b][2048 + w * 512]);
    gload16(pb0 + kt, &Bs[b][w * 512]);
    gload16(pb1 + kt, &Bs[b][2048 + w * 512]);
  };

  stage(0, 0);

  int buf = 0;
  for (int kt = 0; kt < K; kt += 32) {
    __syncthreads();
    if (kt + 32 < K) stage(buf ^ 1, kt + 32);

    const u16* as = &As[buf][0];
    const u16* bs = &Bs[buf][0];

    s16x8 af[4], bf[4];
#pragma unroll
    for (int m = 0; m < 4; ++m) {
      const int row = wr + m * 16 + li;
      af[m] = *(const s16x8*)(as + row * 32 + 8 * (g ^ (row & 3)));
    }
#pragma unroll
    for (int n = 0; n < 4; ++n) {
      const int row = wc + n * 16 + li;
      bf[n] = *(const s16x8*)(bs + row * 32 + 8 * (g ^ (row & 3)));
    }
    __builtin_amdgcn_s_setprio(1);
#pragma unroll
    for (int m = 0; m < 4; ++m)
#pragma unroll
      for (int n = 0; n < 4; ++n)
        acc[m][n] = __builtin_amdgcn_mfma_f32_16x16x32_bf16(af[m], bf[n], acc[m][n], 0, 0, 0);
    __builtin_amdgcn_s_setprio(0);

    buf ^= 1;
  }

#pragma unroll
  for (int n = 0; n < 4; ++n) {
    const int col = bn + wc + n * 16 + li;
    const float bv = bias[col];
#pragma unroll
    for (int m = 0; m < 4; ++m) {
      const int row0 = bm + wr + m * 16 + g * 4;
#pragma unroll
      for (int r = 0; r < 4; ++r)
        store_out(C + (size_t)(row0 + r) * N + col, acc[m][n][r] + bv);
    }
  }
}

// ---------------- GEMM 64x128 (occupancy variant for skinny-N): same template math ----------------
template <typename OutT>
__global__ __launch_bounds__(256) void gemm_bt64(
    const u16* __restrict__ A, const u16* __restrict__ Bt,
    const float* __restrict__ bias, OutT* __restrict__ C,
    int M, int N, int K)
{
  __shared__ u16 As[2][64 * 32];
  __shared__ u16 Bs[2][128 * 32];
  const int tid = threadIdx.x;
  const int w = tid >> 6, l = tid & 63;
  const int g = l >> 4, li = l & 15;
  const int bm = blockIdx.y * 64, bn = blockIdx.x * 128;
  const int wr = (w >> 1) * 32, wc = (w & 1) * 64;   // wave quadrant: 32 rows x 64 cols

  f32x4 acc[2][4] = {};

  // A: 64 rows -> 256 chunks, 1 per thread; B: 128 rows -> 512 chunks, 2 per thread.
  const int ar = tid >> 2,           asl = tid & 3;
  const int br0 = tid >> 2,          bs0 = tid & 3;
  const int br1 = (tid + 256) >> 2,  bs1 = (tid + 256) & 3;
  const u16* pa  = A  + (size_t)(bm + ar)  * K + 8 * (asl ^ (ar  & 3));
  const u16* pb0 = Bt + (size_t)(bn + br0) * K + 8 * (bs0 ^ (br0 & 3));
  const u16* pb1 = Bt + (size_t)(bn + br1) * K + 8 * (bs1 ^ (br1 & 3));

  auto stage = [&](int b, int kt) {
    gload16(pa  + kt, &As[b][w * 512]);
    gload16(pb0 + kt, &Bs[b][w * 512]);
    gload16(pb1 + kt, &Bs[b][2048 + w * 512]);
  };

  stage(0, 0);

  int buf = 0;
  for (int kt = 0; kt < K; kt += 32) {
    __syncthreads();
    if (kt + 32 < K) stage(buf ^ 1, kt + 32);

    const u16* as = &As[buf][0];
    const u16* bs = &Bs[buf][0];

    s16x8 af[2], bf[4];
#pragma unroll
    for (int m = 0; m < 2; ++m) {
      const int row = wr + m * 16 + li;
      af[m] = *(const s16x8*)(as + row * 32 + 8 * (g ^ (row & 3)));
    }
#pragma unroll
    for (int n = 0; n < 4; ++n) {
      const int row = wc + n * 16 + li;
      bf[n] = *(const s16x8*)(bs + row * 32 + 8 * (g ^ (row & 3)));
    }
    __builtin_amdgcn_s_setprio(1);
#pragma unroll
    for (int m = 0; m < 2; ++m)
#pragma unroll
      for (int n = 0; n < 4; ++n)
        acc[m][n] = __builtin_amdgcn_mfma_f32_16x16x32_bf16(af[m], bf[n], acc[m][n], 0, 0, 0);
    __builtin_amdgcn_s_setprio(0);

    buf ^= 1;
  }

#pragma unroll
  for (int n = 0; n < 4; ++n) {
    const int col = bn + wc + n * 16 + li;
    const float bv = bias[col];
#pragma unroll
    for (int m = 0; m < 2; ++m) {
      const int row0 = bm + wr + m * 16 + g * 4;
#pragma unroll
      for (int r = 0; r < 4; ++r)
        store_out(C + (size_t)(row0 + r) * N + col, acc[m][n][r] + bv);
    }
  }
}

// ---------------- flash attention (r13-verified best: 74.1 µs) ----------------
__global__ __launch_bounds__(256, 4) void attn_kernel(
    const u16* __restrict__ qkv, u16* __restrict__ outp)
{
  __shared__ u16 Ks[2][4096];   // [kv][d] dbuf, 16B chunks XOR-swizzled by (kv&7)  (verified)
  __shared__ u16 Vt[4096];      // [d][kv] single, byte XOR ((d^(d>>3))&7)<<4       (verified)
  __shared__ u16 Pl[4 * 1024];  // per-wave P[q=li][64kv], byte XOR ((li&7)<<4)     (verified)

  const int tid = threadIdx.x;
  const int w = tid >> 6, l = tid & 63;
  const int g = l >> 4, li = l & 15;

  // T1: bijective XCD swizzle (1024 = 8 * 128)
  const int lb = (blockIdx.x & 7) * 128 + (blockIdx.x >> 3);
  const int qt = lb & 31;
  const int h  = (lb >> 5) & 15;
  const int bb = lb >> 9;
  const size_t baserow = (size_t)bb * 2048;

  const int qbase = qt * 64 + w * 16;
  const u16* qp = qkv + (baserow + qbase + li) * 3072 + h * 64 + 8 * g;
  const s16x8 qf0 = *(const s16x8*)(qp);
  const s16x8 qf1 = *(const s16x8*)(qp + 32);

  const int kr0 = tid >> 3,         kc0 = tid & 7;
  const int kr1 = (tid + 256) >> 3, kc1 = (tid + 256) & 7;
  const u16* kg0 = qkv + (baserow + kr0) * 3072 + 1024 + h * 64 + 8 * (kc0 ^ (kr0 & 7));
  const u16* kg1 = qkv + (baserow + kr1) * 3072 + 1024 + h * 64 + 8 * (kc1 ^ (kr1 & 7));

  const int vp = tid >> 3, dg = tid & 7;
  const u16* vgA = qkv + (baserow + 2 * vp)     * 3072 + 2048 + h * 64 + 8 * dg;
  const u16* vgB = qkv + (baserow + 2 * vp + 1) * 3072 + 2048 + h * 64 + 8 * dg;

  auto issueK = [&](int b, int t) {
    const size_t koff = (size_t)t * (64 * 3072);
    gload16(kg0 + koff, &Ks[b][w * 512]);
    gload16(kg1 + koff, &Ks[b][2048 + w * 512]);
  };

  const float C1  = 0.18033688f;   // 0.125 * log2(e)
  const float THR = 11.5416f;      // 8 * log2(e)
  float M = -1e30f;
  f32x4 o[4] = {}, os = {};        // o[nd][r] = O[q=li][d=nd*16+4g+r]; os[0] = rowsum

  s16x8 ones;
#pragma unroll
  for (int j = 0; j < 8; ++j) ones[j] = (short)0x3F80;   // bf16 1.0

  char* Pw = (char*)(Pl + w * 1024);
  const int pswz = (li & 7) << 4;

  issueK(0, 0);
  s16x8 va = *(const s16x8*)vgA;
  s16x8 vb = *(const s16x8*)vgB;

  int buf = 0;
  for (int t = 0; t < 32; ++t) {
#pragma unroll
    for (int j = 0; j < 8; ++j) {
      const int d = 8 * dg + j;
      const u32 val = (u32)(u16)va[j] | ((u32)(u16)vb[j] << 16);
      *(u32*)((char*)Vt + d * 128 + ((4 * vp) ^ ((((d ^ (d >> 3)) & 7)) << 4))) = val;
    }
    __syncthreads();   // K[buf] gload drained; Vt visible

    if (t < 31) {
      issueK(buf ^ 1, t + 1);
      const size_t koff = (size_t)(t + 1) * (64 * 3072);
      va = *(const s16x8*)(vgA + koff);
      vb = *(const s16x8*)(vgB + koff);
    }

    const u16* kb = &Ks[buf][0];

    f32x4 s[4] = {};
    __builtin_amdgcn_s_setprio(1);
#pragma unroll
    for (int nk = 0; nk < 4; ++nk) {
      const int kvr = nk * 16 + li;
      const s16x8 kf0 = *(const s16x8*)((const char*)kb + kvr * 128 + 16 * ((0 + g) ^ (kvr & 7)));
      const s16x8 kf1 = *(const s16x8*)((const char*)kb + kvr * 128 + 16 * ((4 + g) ^ (kvr & 7)));
      s[nk] = __builtin_amdgcn_mfma_f32_16x16x32_bf16(kf0, qf0, s[nk], 0, 0, 0);
      s[nk] = __builtin_amdgcn_mfma_f32_16x16x32_bf16(kf1, qf1, s[nk], 0, 0, 0);
    }
    __builtin_amdgcn_s_setprio(0);

    float lm = fmaxf(fmaxf(s[0][0], s[0][1]), fmaxf(s[0][2], s[0][3]));
#pragma unroll
    for (int nk = 1; nk < 4; ++nk)
      lm = fmaxf(lm, fmaxf(fmaxf(s[nk][0], s[nk][1]), fmaxf(s[nk][2], s[nk][3])));
    lm = fmaxf(lm, __shfl_xor(lm, 16));
    lm = fmaxf(lm, __shfl_xor(lm, 32));
    lm *= C1;

    if (__any(lm > M + THR)) {
      const float mn = fmaxf(M, lm);
      const float a = exp2g(M - mn);
      M = mn;
      os[0] *= a;
#pragma unroll
      for (int nd = 0; nd < 4; ++nd)
#pragma unroll
        for (int r = 0; r < 4; ++r) o[nd][r] *= a;
    }

#pragma unroll
    for (int nk = 0; nk < 4; ++nk)
#pragma unroll
      for (int r = 0; r < 4; ++r)
        s[nk][r] = exp2g(fmaf(s[nk][r], C1, -M));

#pragma unroll
    for (int nk = 0; nk < 4; ++nk) {
      u32 lo, hi;
      asm("v_cvt_pk_bf16_f32 %0, %1, %2" : "=v"(lo) : "v"(s[nk][0]), "v"(s[nk][1]));
      asm("v_cvt_pk_bf16_f32 %0, %1, %2" : "=v"(hi) : "v"(s[nk][2]), "v"(s[nk][3]));
      *(u32x2*)(Pw + li * 128 + ((nk * 32 + 8 * g) ^ pswz)) = (u32x2){lo, hi};
    }
    asm volatile("s_waitcnt lgkmcnt(0)" ::: "memory");

    __builtin_amdgcn_s_setprio(1);
#pragma unroll
    for (int ks = 0; ks < 2; ++ks) {
      const s16x8 pf = *(const s16x8*)(Pw + li * 128 + ((ks * 64 + 16 * g) ^ pswz));
#pragma unroll
      for (int nd = 0; nd < 4; ++nd) {
        const int d = nd * 16 + li;
        const s16x8 vf = *(const s16x8*)((char*)Vt + d * 128 + ((ks * 64 + 16 * g) ^ (((d ^ (d >> 3)) & 7) << 4)));
        o[nd] = __builtin_amdgcn_mfma_f32_16x16x32_bf16(vf, pf, o[nd], 0, 0, 0);
      }
      os = __builtin_amdgcn_mfma_f32_16x16x32_bf16(ones, pf, os, 0, 0, 0);
    }
    __builtin_amdgcn_s_setprio(0);

    __syncthreads();
    buf ^= 1;
  }

  const float inv = 1.0f / os[0];
  const size_t row = baserow + qbase + li;
#pragma unroll
  for (int nd = 0; nd < 4; ++nd) {
    ushort4 st;
    st.x = f2bf(o[nd][0] * inv);
    st.y = f2bf(o[nd][1] * inv);
    st.z = f2bf(o[nd][2] * inv);
    st.w = f2bf(o[nd][3] * inv);
    *(ushort4*)(outp + row * 1024 + h * 64 + nd * 16 + 4 * g) = st;
  }
}

// ---------------- launcher ----------------
extern "C" void kernel_launch(void* const* d_in, const int* in_sizes, int n_in,
                              void* d_out, int out_size, void* d_ws, size_t ws_size,
                              hipStream_t stream)
{
  const float* x     = (const float*)d_in[0];
  const float* gamma = (const float*)d_in[1];
  const float* beta  = (const float*)d_in[2];
  const float* Wqkv  = (const float*)d_in[3];
  const float* bqkv  = (const float*)d_in[4];
  const float* Wout  = (const float*)d_in[5];
  const float* bout  = (const float*)d_in[6];
  float* out = (float*)d_out;

  char* ws = (char*)d_ws;
  u16* xn     = (u16*)(ws);                       // 8 MB  [4096][1024]
  u16* wqkv_t = (u16*)(ws + ((size_t)8  << 20));  // 6 MB  [3072][1024]
  u16* wout_t = (u16*)(ws + ((size_t)14 << 20));  // 2 MB  [1024][1024]
  u16* qkv    = (u16*)(ws + ((size_t)16 << 20));  // 24 MB [4096][3072]
  u16* attn   = (u16*)(ws + ((size_t)40 << 20));  // 8 MB  [4096][1024]

  ln_kernel<<<4096, 256, 0, stream>>>(x, gamma, beta, xn);
  transpose_cvt<<<dim3(96, 32), dim3(32, 8), 0, stream>>>(Wqkv, wqkv_t, 1024, 3072);
  transpose_cvt<<<dim3(32, 32), dim3(32, 8), 0, stream>>>(Wout, wout_t, 1024, 1024);
  gemm_bt<u16><<<dim3(24, 32), 256, 0, stream>>>(xn, wqkv_t, bqkv, qkv, 4096, 3072, 1024);
  attn_kernel<<<1024, 256, 0, stream>>>(qkv, attn);
  gemm_bt64<float><<<dim3(8, 64), 256, 0, stream>>>(attn, wout_t, bout, out, 4096, 1024, 1024);
}

// Round 17
// 131.631 us; speedup vs baseline: 1.0771x; 1.0093x over previous
//
#include <hip/hip_runtime.h>

typedef unsigned short u16;
typedef unsigned int   u32;
typedef __attribute__((ext_vector_type(2)))  unsigned u32x2;
typedef __attribute__((ext_vector_type(4)))  float  f32x4;
typedef __attribute__((ext_vector_type(8)))  short  s16x8;

__device__ __forceinline__ u16 f2bf(float f) {
  unsigned u = __builtin_bit_cast(unsigned, f);
  u += 0x7FFFu + ((u >> 16) & 1u);
  return (u16)(u >> 16);
}

__device__ __forceinline__ float exp2g(float x) { return __builtin_amdgcn_exp2f(x); }

__device__ __forceinline__ void gload16(const void* g, void* l) {
  __builtin_amdgcn_global_load_lds(
      (const __attribute__((address_space(1))) void*)g,
      (__attribute__((address_space(3))) void*)l, 16, 0, 0);
}

// ---------------- LayerNorm (fp32 in -> bf16 out) ----------------
__global__ __launch_bounds__(256) void ln_kernel(
    const float* __restrict__ x, const float* __restrict__ gamma,
    const float* __restrict__ beta, u16* __restrict__ xn)
{
  const int row = blockIdx.x, tid = threadIdx.x;
  const float* xr = x + (size_t)row * 1024;
  float4 v = *(const float4*)(xr + tid * 4);
  float s  = v.x + v.y + v.z + v.w;
  float s2 = v.x*v.x + v.y*v.y + v.z*v.z + v.w*v.w;
#pragma unroll
  for (int off = 32; off >= 1; off >>= 1) {
    s  += __shfl_xor(s,  off);
    s2 += __shfl_xor(s2, off);
  }
  __shared__ float red[8];
  const int w = tid >> 6, l = tid & 63;
  if (l == 0) { red[w] = s; red[w + 4] = s2; }
  __syncthreads();
  s  = red[0] + red[1] + red[2] + red[3];
  s2 = red[4] + red[5] + red[6] + red[7];
  const float mu  = s * (1.0f / 1024.0f);
  const float var = s2 * (1.0f / 1024.0f) - mu * mu;
  const float rs  = rsqrtf(var + 1e-5f);
  float4 g  = *(const float4*)(gamma + tid * 4);
  float4 be = *(const float4*)(beta  + tid * 4);
  ushort4 o;
  o.x = f2bf((v.x - mu) * rs * g.x + be.x);
  o.y = f2bf((v.y - mu) * rs * g.y + be.y);
  o.z = f2bf((v.z - mu) * rs * g.z + be.z);
  o.w = f2bf((v.w - mu) * rs * g.w + be.w);
  *(ushort4*)(xn + (size_t)row * 1024 + tid * 4) = o;
}

// ---------------- transpose + fp32->bf16 convert ----------------
__global__ void transpose_cvt(const float* __restrict__ in, u16* __restrict__ out,
                              int R, int C)
{
  __shared__ float t[32][33];
  const int bc = blockIdx.x * 32, br = blockIdx.y * 32;
  const int x = threadIdx.x;
#pragma unroll
  for (int i = threadIdx.y; i < 32; i += 8)
    t[i][x] = in[(size_t)(br + i) * C + bc + x];
  __syncthreads();
#pragma unroll
  for (int i = threadIdx.y; i < 32; i += 8)
    out[(size_t)(bc + i) * R + br + x] = f2bf(t[x][i]);
}

// ---------------- GEMM 128x128, counted-vmcnt pipeline (T4 on r12 skeleton) ----------------
__device__ __forceinline__ void store_out(float* p, float v) { *p = v; }
__device__ __forceinline__ void store_out(u16* p, float v)   { *p = f2bf(v); }

template <typename OutT>
__global__ __launch_bounds__(256) void gemm_bt(
    const u16* __restrict__ A, const u16* __restrict__ Bt,
    const float* __restrict__ bias, OutT* __restrict__ C,
    int M, int N, int K)
{
  __shared__ u16 As[2][128 * 32];
  __shared__ u16 Bs[2][128 * 32];
  const int tid = threadIdx.x;
  const int w = tid >> 6, l = tid & 63;
  const int g = l >> 4, li = l & 15;
  const int bm = blockIdx.y * 128, bn = blockIdx.x * 128;
  const int wr = (w >> 1) * 64, wc = (w & 1) * 64;

  f32x4 acc[4][4] = {};

  const int ar0 = tid >> 2,          as0 = tid & 3;
  const int ar1 = (tid + 256) >> 2,  as1 = (tid + 256) & 3;
  const u16* pa0 = A  + (size_t)(bm + ar0) * K + 8 * (as0 ^ (ar0 & 3));
  const u16* pa1 = A  + (size_t)(bm + ar1) * K + 8 * (as1 ^ (ar1 & 3));
  const u16* pb0 = Bt + (size_t)(bn + ar0) * K + 8 * (as0 ^ (ar0 & 3));
  const u16* pb1 = Bt + (size_t)(bn + ar1) * K + 8 * (as1 ^ (ar1 & 3));

  auto stage = [&](int b, int kt) {    // 4 gloads per wave per tile
    gload16(pa0 + kt, &As[b][w * 512]);
    gload16(pa1 + kt, &As[b][2048 + w * 512]);
    gload16(pb0 + kt, &Bs[b][w * 512]);
    gload16(pb1 + kt, &Bs[b][2048 + w * 512]);
  };

  // prologue: 2 tiles in flight (8 outstanding loads/wave)
  stage(0, 0);
  if (K > 32) stage(1, 32);

  int buf = 0;
  for (int kt = 0; kt < K; kt += 32) {
    // T4: counted wait — own 4 loads of THIS tile landed; next tile's 4 stay in flight.
    // wait-before-barrier => after the barrier, every wave's quarter is resident.
    if (kt + 32 < K) asm volatile("s_waitcnt vmcnt(4)" ::: "memory");
    else             asm volatile("s_waitcnt vmcnt(0)" ::: "memory");
    __builtin_amdgcn_s_barrier();

    const u16* as = &As[buf][0];
    const u16* bs = &Bs[buf][0];

    s16x8 af[4], bf[4];
#pragma unroll
    for (int m = 0; m < 4; ++m) {
      const int row = wr + m * 16 + li;
      af[m] = *(const s16x8*)(as + row * 32 + 8 * (g ^ (row & 3)));
    }
#pragma unroll
    for (int n = 0; n < 4; ++n) {
      const int row = wc + n * 16 + li;
      bf[n] = *(const s16x8*)(bs + row * 32 + 8 * (g ^ (row & 3)));
    }
    __builtin_amdgcn_s_setprio(1);
#pragma unroll
    for (int m = 0; m < 4; ++m)
#pragma unroll
      for (int n = 0; n < 4; ++n)
        acc[m][n] = __builtin_amdgcn_mfma_f32_16x16x32_bf16(af[m], bf[n], acc[m][n], 0, 0, 0);
    __builtin_amdgcn_s_setprio(0);

    __builtin_amdgcn_s_barrier();      // all waves done reading buf (ds_reads retired pre-MFMA)
    if (kt + 64 < K) stage(buf, kt + 64);   // refill freed buffer, 2 tiles ahead
    buf ^= 1;
  }

#pragma unroll
  for (int n = 0; n < 4; ++n) {
    const int col = bn + wc + n * 16 + li;
    const float bv = bias[col];
#pragma unroll
    for (int m = 0; m < 4; ++m) {
      const int row0 = bm + wr + m * 16 + g * 4;
#pragma unroll
      for (int r = 0; r < 4; ++r)
        store_out(C + (size_t)(row0 + r) * N + col, acc[m][n][r] + bv);
    }
  }
}

// ---------------- GEMM 64x128 (occupancy variant), counted-vmcnt pipeline ----------------
template <typename OutT>
__global__ __launch_bounds__(256) void gemm_bt64(
    const u16* __restrict__ A, const u16* __restrict__ Bt,
    const float* __restrict__ bias, OutT* __restrict__ C,
    int M, int N, int K)
{
  __shared__ u16 As[2][64 * 32];
  __shared__ u16 Bs[2][128 * 32];
  const int tid = threadIdx.x;
  const int w = tid >> 6, l = tid & 63;
  const int g = l >> 4, li = l & 15;
  const int bm = blockIdx.y * 64, bn = blockIdx.x * 128;
  const int wr = (w >> 1) * 32, wc = (w & 1) * 64;

  f32x4 acc[2][4] = {};

  const int ar = tid >> 2,           asl = tid & 3;
  const int br0 = tid >> 2,          bs0 = tid & 3;
  const int br1 = (tid + 256) >> 2,  bs1 = (tid + 256) & 3;
  const u16* pa  = A  + (size_t)(bm + ar)  * K + 8 * (asl ^ (ar  & 3));
  const u16* pb0 = Bt + (size_t)(bn + br0) * K + 8 * (bs0 ^ (br0 & 3));
  const u16* pb1 = Bt + (size_t)(bn + br1) * K + 8 * (bs1 ^ (br1 & 3));

  auto stage = [&](int b, int kt) {   // 3 gloads per wave per tile
    gload16(pa  + kt, &As[b][w * 512]);
    gload16(pb0 + kt, &Bs[b][w * 512]);
    gload16(pb1 + kt, &Bs[b][2048 + w * 512]);
  };

  stage(0, 0);
  if (K > 32) stage(1, 32);

  int buf = 0;
  for (int kt = 0; kt < K; kt += 32) {
    if (kt + 32 < K) asm volatile("s_waitcnt vmcnt(3)" ::: "memory");
    else             asm volatile("s_waitcnt vmcnt(0)" ::: "memory");
    __builtin_amdgcn_s_barrier();

    const u16* as = &As[buf][0];
    const u16* bs = &Bs[buf][0];

    s16x8 af[2], bf[4];
#pragma unroll
    for (int m = 0; m < 2; ++m) {
      const int row = wr + m * 16 + li;
      af[m] = *(const s16x8*)(as + row * 32 + 8 * (g ^ (row & 3)));
    }
#pragma unroll
    for (int n = 0; n < 4; ++n) {
      const int row = wc + n * 16 + li;
      bf[n] = *(const s16x8*)(bs + row * 32 + 8 * (g ^ (row & 3)));
    }
    __builtin_amdgcn_s_setprio(1);
#pragma unroll
    for (int m = 0; m < 2; ++m)
#pragma unroll
      for (int n = 0; n < 4; ++n)
        acc[m][n] = __builtin_amdgcn_mfma_f32_16x16x32_bf16(af[m], bf[n], acc[m][n], 0, 0, 0);
    __builtin_amdgcn_s_setprio(0);

    __builtin_amdgcn_s_barrier();
    if (kt + 64 < K) stage(buf, kt + 64);
    buf ^= 1;
  }

#pragma unroll
  for (int n = 0; n < 4; ++n) {
    const int col = bn + wc + n * 16 + li;
    const float bv = bias[col];
#pragma unroll
    for (int m = 0; m < 2; ++m) {
      const int row0 = bm + wr + m * 16 + g * 4;
#pragma unroll
      for (int r = 0; r < 4; ++r)
        store_out(C + (size_t)(row0 + r) * N + col, acc[m][n][r] + bv);
    }
  }
}

// ---------------- flash attention (r13-verified best: ~74 µs, frozen) ----------------
__global__ __launch_bounds__(256, 4) void attn_kernel(
    const u16* __restrict__ qkv, u16* __restrict__ outp)
{
  __shared__ u16 Ks[2][4096];   // [kv][d] dbuf, 16B chunks XOR-swizzled by (kv&7)  (verified)
  __shared__ u16 Vt[4096];      // [d][kv] single, byte XOR ((d^(d>>3))&7)<<4       (verified)
  __shared__ u16 Pl[4 * 1024];  // per-wave P[q=li][64kv], byte XOR ((li&7)<<4)     (verified)

  const int tid = threadIdx.x;
  const int w = tid >> 6, l = tid & 63;
  const int g = l >> 4, li = l & 15;

  // T1: bijective XCD swizzle (1024 = 8 * 128)
  const int lb = (blockIdx.x & 7) * 128 + (blockIdx.x >> 3);
  const int qt = lb & 31;
  const int h  = (lb >> 5) & 15;
  const int bb = lb >> 9;
  const size_t baserow = (size_t)bb * 2048;

  const int qbase = qt * 64 + w * 16;
  const u16* qp = qkv + (baserow + qbase + li) * 3072 + h * 64 + 8 * g;
  const s16x8 qf0 = *(const s16x8*)(qp);
  const s16x8 qf1 = *(const s16x8*)(qp + 32);

  const int kr0 = tid >> 3,         kc0 = tid & 7;
  const int kr1 = (tid + 256) >> 3, kc1 = (tid + 256) & 7;
  const u16* kg0 = qkv + (baserow + kr0) * 3072 + 1024 + h * 64 + 8 * (kc0 ^ (kr0 & 7));
  const u16* kg1 = qkv + (baserow + kr1) * 3072 + 1024 + h * 64 + 8 * (kc1 ^ (kr1 & 7));

  const int vp = tid >> 3, dg = tid & 7;
  const u16* vgA = qkv + (baserow + 2 * vp)     * 3072 + 2048 + h * 64 + 8 * dg;
  const u16* vgB = qkv + (baserow + 2 * vp + 1) * 3072 + 2048 + h * 64 + 8 * dg;

  auto issueK = [&](int b, int t) {
    const size_t koff = (size_t)t * (64 * 3072);
    gload16(kg0 + koff, &Ks[b][w * 512]);
    gload16(kg1 + koff, &Ks[b][2048 + w * 512]);
  };

  const float C1  = 0.18033688f;   // 0.125 * log2(e)
  const float THR = 11.5416f;      // 8 * log2(e)
  float M = -1e30f;
  f32x4 o[4] = {}, os = {};        // o[nd][r] = O[q=li][d=nd*16+4g+r]; os[0] = rowsum

  s16x8 ones;
#pragma unroll
  for (int j = 0; j < 8; ++j) ones[j] = (short)0x3F80;   // bf16 1.0

  char* Pw = (char*)(Pl + w * 1024);
  const int pswz = (li & 7) << 4;

  issueK(0, 0);
  s16x8 va = *(const s16x8*)vgA;
  s16x8 vb = *(const s16x8*)vgB;

  int buf = 0;
  for (int t = 0; t < 32; ++t) {
#pragma unroll
    for (int j = 0; j < 8; ++j) {
      const int d = 8 * dg + j;
      const u32 val = (u32)(u16)va[j] | ((u32)(u16)vb[j] << 16);
      *(u32*)((char*)Vt + d * 128 + ((4 * vp) ^ ((((d ^ (d >> 3)) & 7)) << 4))) = val;
    }
    __syncthreads();   // K[buf] gload drained; Vt visible

    if (t < 31) {
      issueK(buf ^ 1, t + 1);
      const size_t koff = (size_t)(t + 1) * (64 * 3072);
      va = *(const s16x8*)(vgA + koff);
      vb = *(const s16x8*)(vgB + koff);
    }

    const u16* kb = &Ks[buf][0];

    f32x4 s[4] = {};
    __builtin_amdgcn_s_setprio(1);
#pragma unroll
    for (int nk = 0; nk < 4; ++nk) {
      const int kvr = nk * 16 + li;
      const s16x8 kf0 = *(const s16x8*)((const char*)kb + kvr * 128 + 16 * ((0 + g) ^ (kvr & 7)));
      const s16x8 kf1 = *(const s16x8*)((const char*)kb + kvr * 128 + 16 * ((4 + g) ^ (kvr & 7)));
      s[nk] = __builtin_amdgcn_mfma_f32_16x16x32_bf16(kf0, qf0, s[nk], 0, 0, 0);
      s[nk] = __builtin_amdgcn_mfma_f32_16x16x32_bf16(kf1, qf1, s[nk], 0, 0, 0);
    }
    __builtin_amdgcn_s_setprio(0);

    float lm = fmaxf(fmaxf(s[0][0], s[0][1]), fmaxf(s[0][2], s[0][3]));
#pragma unroll
    for (int nk = 1; nk < 4; ++nk)
      lm = fmaxf(lm, fmaxf(fmaxf(s[nk][0], s[nk][1]), fmaxf(s[nk][2], s[nk][3])));
    lm = fmaxf(lm, __shfl_xor(lm, 16));
    lm = fmaxf(lm, __shfl_xor(lm, 32));
    lm *= C1;

    if (__any(lm > M + THR)) {
      const float mn = fmaxf(M, lm);
      const float a = exp2g(M - mn);
      M = mn;
      os[0] *= a;
#pragma unroll
      for (int nd = 0; nd < 4; ++nd)
#pragma unroll
        for (int r = 0; r < 4; ++r) o[nd][r] *= a;
    }

#pragma unroll
    for (int nk = 0; nk < 4; ++nk)
#pragma unroll
      for (int r = 0; r < 4; ++r)
        s[nk][r] = exp2g(fmaf(s[nk][r], C1, -M));

#pragma unroll
    for (int nk = 0; nk < 4; ++nk) {
      u32 lo, hi;
      asm("v_cvt_pk_bf16_f32 %0, %1, %2" : "=v"(lo) : "v"(s[nk][0]), "v"(s[nk][1]));
      asm("v_cvt_pk_bf16_f32 %0, %1, %2" : "=v"(hi) : "v"(s[nk][2]), "v"(s[nk][3]));
      *(u32x2*)(Pw + li * 128 + ((nk * 32 + 8 * g) ^ pswz)) = (u32x2){lo, hi};
    }
    asm volatile("s_waitcnt lgkmcnt(0)" ::: "memory");

    __builtin_amdgcn_s_setprio(1);
#pragma unroll
    for (int ks = 0; ks < 2; ++ks) {
      const s16x8 pf = *(const s16x8*)(Pw + li * 128 + ((ks * 64 + 16 * g) ^ pswz));
#pragma unroll
      for (int nd = 0; nd < 4; ++nd) {
        const int d = nd * 16 + li;
        const s16x8 vf = *(const s16x8*)((char*)Vt + d * 128 + ((ks * 64 + 16 * g) ^ (((d ^ (d >> 3)) & 7) << 4)));
        o[nd] = __builtin_amdgcn_mfma_f32_16x16x32_bf16(vf, pf, o[nd], 0, 0, 0);
      }
      os = __builtin_amdgcn_mfma_f32_16x16x32_bf16(ones, pf, os, 0, 0, 0);
    }
    __builtin_amdgcn_s_setprio(0);

    __syncthreads();
    buf ^= 1;
  }

  const float inv = 1.0f / os[0];
  const size_t row = baserow + qbase + li;
#pragma unroll
  for (int nd = 0; nd < 4; ++nd) {
    ushort4 st;
    st.x = f2bf(o[nd][0] * inv);
    st.y = f2bf(o[nd][1] * inv);
    st.z = f2bf(o[nd][2] * inv);
    st.w = f2bf(o[nd][3] * inv);
    *(ushort4*)(outp + row * 1024 + h * 64 + nd * 16 + 4 * g) = st;
  }
}

// ---------------- launcher ----------------
extern "C" void kernel_launch(void* const* d_in, const int* in_sizes, int n_in,
                              void* d_out, int out_size, void* d_ws, size_t ws_size,
                              hipStream_t stream)
{
  const float* x     = (const float*)d_in[0];
  const float* gamma = (const float*)d_in[1];
  const float* beta  = (const float*)d_in[2];
  const float* Wqkv  = (const float*)d_in[3];
  const float* bqkv  = (const float*)d_in[4];
  const float* Wout  = (const float*)d_in[5];
  const float* bout  = (const float*)d_in[6];
  float* out = (float*)d_out;

  char* ws = (char*)d_ws;
  u16* xn     = (u16*)(ws);                       // 8 MB  [4096][1024]
  u16* wqkv_t = (u16*)(ws + ((size_t)8  << 20));  // 6 MB  [3072][1024]
  u16* wout_t = (u16*)(ws + ((size_t)14 << 20));  // 2 MB  [1024][1024]
  u16* qkv    = (u16*)(ws + ((size_t)16 << 20));  // 24 MB [4096][3072]
  u16* attn   = (u16*)(ws + ((size_t)40 << 20));  // 8 MB  [4096][1024]

  ln_kernel<<<4096, 256, 0, stream>>>(x, gamma, beta, xn);
  transpose_cvt<<<dim3(96, 32), dim3(32, 8), 0, stream>>>(Wqkv, wqkv_t, 1024, 3072);
  transpose_cvt<<<dim3(32, 32), dim3(32, 8), 0, stream>>>(Wout, wout_t, 1024, 1024);
  gemm_bt<u16><<<dim3(24, 32), 256, 0, stream>>>(xn, wqkv_t, bqkv, qkv, 4096, 3072, 1024);
  attn_kernel<<<1024, 256, 0, stream>>>(qkv, attn);
  gemm_bt64<float><<<dim3(8, 64), 256, 0, stream>>>(attn, wout_t, bout, out, 4096, 1024, 1024);
}